// Round 5
// baseline (70.263 us; speedup 1.0000x reference)
//
#include <hip/hip_runtime.h>

#define NB   2        // batches
#define GG   128      // grid extent
#define CC   128      // channels
#define QPB  64       // queries per block in fused query kernel

typedef float v4f __attribute__((ext_vector_type(4)));

constexpr int OCC_INTS = NB * GG * GG * GG;   // 16 MiB

// ---- K0: init occ = -1, out_acc = 0, shift = INT_MAX ------------------------
__global__ void __launch_bounds__(256)
init_kernel(int* __restrict__ occ, float* __restrict__ acc,
            int* __restrict__ shift, int n) {
    const int tid = blockIdx.x * 256 + threadIdx.x;
    const int nth = gridDim.x * 256;
    if (tid < NB * 3) shift[tid] = 0x7FFFFFFF;
    int4* occ4 = (int4*)occ;
    for (int i = tid; i < OCC_INTS / 4; i += nth)
        occ4[i] = make_int4(-1, -1, -1, -1);
    for (int i = tid; i < n; i += nth) acc[i] = 0.0f;
}

// ---- K1: fused shift-min + UNSHIFTED occupancy scatter ----------------------
__global__ void __launch_bounds__(256)
scatter_kernel(const int4* __restrict__ coords, int* __restrict__ shift,
               int* __restrict__ occ, int n) {
    __shared__ int smin[NB * 3];
    if (threadIdx.x < NB * 3) smin[threadIdx.x] = 0x7FFFFFFF;
    __syncthreads();
    for (int i = blockIdx.x * 256 + threadIdx.x; i < n; i += gridDim.x * 256) {
        const int4 c = coords[i];                  // (b, x, y, z)
        atomicMin(&smin[c.x * 3 + 0], c.y);
        atomicMin(&smin[c.x * 3 + 1], c.z);
        atomicMin(&smin[c.x * 3 + 2], c.w);
        atomicMax(&occ[((c.x * GG + c.y) * GG + c.z) * GG + c.w], i);
    }
    __syncthreads();
    if (threadIdx.x < NB * 3) atomicMin(&shift[threadIdx.x], smin[threadIdx.x]);
}

// ---- K2: fused corner + gather, branch-free predicated loads ----------------
__global__ void __launch_bounds__(256)
query_kernel(const float* __restrict__ feats,
             const v4f* __restrict__ qpts,
             const int* __restrict__ shift,
             const int* __restrict__ occ,
             float* __restrict__ out_qf,
             float* __restrict__ out_idx,
             float* __restrict__ out_w,
             float* __restrict__ out_acc, int mq) {
    __shared__ int   s_idx[QPB][8];
    __shared__ float s_w[QPB][8];
    const int tid   = threadIdx.x;
    const int qbase = blockIdx.x * QPB;

    // ---------------- phase 1: one wave, 1 thread/query, 8-deep occ loads ----
    if (tid < QPB) {
        const int gq = qbase + tid;
        int   lidx[8];
        float lw[8];
#pragma unroll
        for (int cn = 0; cn < 8; ++cn) { lidx[cn] = -1; lw[cn] = 0.0f; }
        if (gq < mq) {
            const v4f qp = qpts[gq];
            const int qb = (int)qp.x;
            const int s0 = shift[qb * 3 + 0], s1 = shift[qb * 3 + 1],
                      s2 = shift[qb * 3 + 2];
            const float q0 = qp.y - (float)s0, q1 = qp.z - (float)s1,
                        q2 = qp.w - (float)s2;
            const float b0 = floorf(q0), b1 = floorf(q1), b2 = floorf(q2);
            const float f0 = q0 - b0, f1 = q1 - b1, f2 = q2 - b2;
            const int i0 = (int)b0, i1 = (int)b1, i2 = (int)b2;
            const int u0 = i0 + s0, u1 = i1 + s1, u2 = i2 + s2;  // unshifted
#pragma unroll
            for (int cn = 0; cn < 8; ++cn) {
                const int oi = (cn >> 2) & 1, oj = (cn >> 1) & 1, ok = cn & 1;
                const int c0 = i0 + oi, c1 = i1 + oj, c2 = i2 + ok; // ref space
                const int a0 = u0 + oi, a1 = u1 + oj, a2 = u2 + ok; // occ addr
                const float w = (oi ? f0 : 1.0f - f0) *
                                (oj ? f1 : 1.0f - f1) *
                                (ok ? f2 : 1.0f - f2);
                const bool inb = c0 >= 0 && c0 < GG && c1 >= 0 && c1 < GG &&
                                 c2 >= 0 && c2 < GG &&
                                 a0 < GG && a1 < GG && a2 < GG;
                // clamp address, load unconditionally, select by mask
                const int p0 = min(max(a0, 0), GG - 1);
                const int p1 = min(max(a1, 0), GG - 1);
                const int p2 = min(max(a2, 0), GG - 1);
                int idx = occ[((qb * GG + p0) * GG + p1) * GG + p2];
                idx = inb ? idx : -1;
                const float fw = (idx != -1) ? w : 0.0f;
                lidx[cn] = idx;
                lw[cn]   = fw;
            }
#pragma unroll
            for (int cn = 0; cn < 8; ++cn)
                if (lidx[cn] >= 0 && lw[cn] != 0.0f)
                    atomicAdd(&out_acc[lidx[cn]], lw[cn]);
            const v4f vi0 = {(float)lidx[0], (float)lidx[1], (float)lidx[2], (float)lidx[3]};
            const v4f vi1 = {(float)lidx[4], (float)lidx[5], (float)lidx[6], (float)lidx[7]};
            const v4f vw0 = {lw[0], lw[1], lw[2], lw[3]};
            const v4f vw1 = {lw[4], lw[5], lw[6], lw[7]};
            __builtin_nontemporal_store(vi0, (v4f*)&out_idx[(size_t)gq * 8]);
            __builtin_nontemporal_store(vi1, (v4f*)&out_idx[(size_t)gq * 8 + 4]);
            __builtin_nontemporal_store(vw0, (v4f*)&out_w[(size_t)gq * 8]);
            __builtin_nontemporal_store(vw1, (v4f*)&out_w[(size_t)gq * 8 + 4]);
        }
#pragma unroll
        for (int cn = 0; cn < 8; ++cn) {
            s_idx[tid][cn] = lidx[cn];
            s_w[tid][cn]   = lw[cn];
        }
    }
    __syncthreads();

    // ---------------- phase 2: batched predicated float4 gathers -------------
    const int lane = tid & 31;
    const int qsub = tid >> 5;        // 0..7
    const int c4   = lane << 2;       // channel*4

#define LOADQ(F, W, Q) do {                                                   \
    _Pragma("unroll")                                                         \
    for (int k = 0; k < 8; ++k) {                                             \
        const int idx_ = s_idx[(Q)][k];                                       \
        (W)[k] = s_w[(Q)][k];                                                 \
        const int safe_ = idx_ < 0 ? 0 : idx_;                                \
        (F)[k] = *(const v4f*)&feats[(size_t)safe_ * CC + c4];                 \
    } } while (0)

#define ACCST(F, W, GQ) do {                                                  \
    v4f acc_ = {0.0f, 0.0f, 0.0f, 0.0f};                                      \
    _Pragma("unroll")                                                         \
    for (int k = 0; k < 8; ++k) acc_ += (W)[k] * (F)[k];                      \
    __builtin_nontemporal_store(acc_, (v4f*)&out_qf[(size_t)(GQ) * CC + c4]); \
    } while (0)

    if (qbase + QPB <= mq) {          // fast path: full block, branch-free
        v4f   fA[8], fB[8];
        float wA[8], wB[8];
        LOADQ(fA, wA, qsub);                       // p = 0
#pragma unroll
        for (int pp = 0; pp < 4; ++pp) {
            const int qE = pp * 16 + qsub;         // p = 2*pp
            const int qO = pp * 16 + 8 + qsub;     // p = 2*pp+1
            LOADQ(fB, wB, qO);
            ACCST(fA, wA, qbase + qE);
            if (pp < 3) LOADQ(fA, wA, (pp + 1) * 16 + qsub);
            ACCST(fB, wB, qbase + qO);
        }
    } else {                          // tail block
#pragma unroll
        for (int p = 0; p < 8; ++p) {
            const int q  = p * 8 + qsub;
            const int gq = qbase + q;
            if (gq >= mq) continue;
            v4f   f[8];
            float w[8];
            LOADQ(f, w, q);
            ACCST(f, w, gq);
        }
    }
#undef LOADQ
#undef ACCST
}

extern "C" void kernel_launch(void* const* d_in, const int* in_sizes, int n_in,
                              void* d_out, int out_size, void* d_ws, size_t ws_size,
                              hipStream_t stream) {
    const float* feats  = (const float*)d_in[0];
    const int4*  coords = (const int4*)d_in[1];
    const v4f*   qpts   = (const v4f*)d_in[2];

    const int n  = in_sizes[1] / 4;  // N points
    const int mq = in_sizes[2] / 4;  // M queries

    float* out     = (float*)d_out;
    float* out_qf  = out;
    float* out_idx = out_qf  + (size_t)mq * CC;
    float* out_w   = out_idx + (size_t)mq * 8;
    float* out_acc = out_w   + (size_t)mq * 8;

    int* shift = (int*)d_ws;
    int* occ   = (int*)((char*)d_ws + 256);

    init_kernel   <<<2048, 256, 0, stream>>>(occ, out_acc, shift, n);
    scatter_kernel<<<(n + 255) / 256, 256, 0, stream>>>(coords, shift, occ, n);
    query_kernel  <<<(mq + QPB - 1) / QPB, 256, 0, stream>>>(
        feats, qpts, shift, occ, out_qf, out_idx, out_w, out_acc, mq);
}

// Round 6
// 63.540 us; speedup vs baseline: 1.1058x; 1.1058x over previous
//
#include <hip/hip_runtime.h>

#define NB   2        // batches
#define GG   128      // grid extent
#define CC   128      // channels
#define QPB  32       // queries per block (block = QPB*8 = 256 threads)
#define BLK  256

typedef float v4f __attribute__((ext_vector_type(4)));

constexpr int OCC_INTS = NB * GG * GG * GG;   // 16 MiB

// ---- K0: init occ = -1, out_acc = 0, shift = INT_MAX ------------------------
__global__ void __launch_bounds__(256)
init_kernel(int* __restrict__ occ, float* __restrict__ acc,
            int* __restrict__ shift, int n) {
    const int tid = blockIdx.x * 256 + threadIdx.x;
    const int nth = gridDim.x * 256;
    if (tid < NB * 3) shift[tid] = 0x7FFFFFFF;
    int4* occ4 = (int4*)occ;
    for (int i = tid; i < OCC_INTS / 4; i += nth)
        occ4[i] = make_int4(-1, -1, -1, -1);
    for (int i = tid; i < n; i += nth) acc[i] = 0.0f;
}

// ---- K1: fused shift-min + UNSHIFTED occupancy scatter ----------------------
// scatter is translation-invariant; queries add shift back into the address.
__global__ void __launch_bounds__(256)
scatter_kernel(const int4* __restrict__ coords, int* __restrict__ shift,
               int* __restrict__ occ, int n) {
    __shared__ int smin[NB * 3];
    if (threadIdx.x < NB * 3) smin[threadIdx.x] = 0x7FFFFFFF;
    __syncthreads();
    for (int i = blockIdx.x * 256 + threadIdx.x; i < n; i += gridDim.x * 256) {
        const int4 c = coords[i];                  // (b, x, y, z)
        atomicMin(&smin[c.x * 3 + 0], c.y);
        atomicMin(&smin[c.x * 3 + 1], c.z);
        atomicMin(&smin[c.x * 3 + 2], c.w);
        atomicMax(&occ[((c.x * GG + c.y) * GG + c.z) * GG + c.w], i);
    }
    __syncthreads();
    if (threadIdx.x < NB * 3) atomicMin(&shift[threadIdx.x], smin[threadIdx.x]);
}

// ---- K2: fused corner + gather with ballot-compacted valid corners ----------
// phase 1: 256 threads = 32 queries x 8 corners, 256 independent occ loads,
//          coalesced idx/w stores, valid (idx,w) compacted into LDS
// phase 2: 8 subgroups x 32 lanes, loop only over the valid corners (avg 0.37)
__global__ void __launch_bounds__(256)
query_kernel(const float* __restrict__ feats,
             const v4f* __restrict__ qpts,
             const int* __restrict__ shift,
             const int* __restrict__ occ,
             float* __restrict__ out_qf,
             float* __restrict__ out_idx,
             float* __restrict__ out_w,
             float* __restrict__ out_acc, int mq) {
    __shared__ int  s_cnt[QPB];
    __shared__ int2 s_pair[QPB][8];
    const int tid   = threadIdx.x;
    const int qbase = blockIdx.x * QPB;
    const int q     = tid >> 3;          // 0..31 query in block
    const int cn    = tid & 7;           // corner
    const int gq    = qbase + q;

    // ---------------- phase 1 ------------------------------------------------
    int   idx = -1;
    float fw  = 0.0f;
    if (gq < mq) {
        const v4f qp = qpts[gq];
        const int qb = (int)qp.x;
        const int s0 = shift[qb * 3 + 0], s1 = shift[qb * 3 + 1],
                  s2 = shift[qb * 3 + 2];
        // reproduce reference arithmetic exactly (shifted space)
        const float q0 = qp.y - (float)s0, q1 = qp.z - (float)s1,
                    q2 = qp.w - (float)s2;
        const float b0 = floorf(q0), b1 = floorf(q1), b2 = floorf(q2);
        const float f0 = q0 - b0, f1 = q1 - b1, f2 = q2 - b2;
        const int i0 = (int)b0, i1 = (int)b1, i2 = (int)b2;
        const int oi = (cn >> 2) & 1, oj = (cn >> 1) & 1, ok = cn & 1;
        const int c0 = i0 + oi, c1 = i1 + oj, c2 = i2 + ok;          // ref space
        const int a0 = c0 + s0, a1 = c1 + s1, a2 = c2 + s2;          // occ addr
        const float w = (oi ? f0 : 1.0f - f0) *
                        (oj ? f1 : 1.0f - f1) *
                        (ok ? f2 : 1.0f - f2);
        const bool inb = c0 >= 0 && c0 < GG && c1 >= 0 && c1 < GG &&
                         c2 >= 0 && c2 < GG &&
                         a0 < GG && a1 < GG && a2 < GG;
        // clamp address, load unconditionally, select by mask
        const int p0 = min(max(a0, 0), GG - 1);
        const int p1 = min(max(a1, 0), GG - 1);
        const int p2 = min(max(a2, 0), GG - 1);
        int v = occ[((qb * GG + p0) * GG + p1) * GG + p2];
        idx = inb ? v : -1;
        fw  = (idx != -1) ? w : 0.0f;

        out_idx[(size_t)gq * 8 + cn] = (float)idx;   // coalesced 1KB/block
        out_w[(size_t)gq * 8 + cn]   = fw;
        if (idx >= 0 && fw != 0.0f) atomicAdd(&out_acc[idx], fw);
    }

    // ballot-compaction within each 8-lane corner group
    const unsigned long long bal = __ballot(idx >= 0);
    const int lane = tid & 63;
    const unsigned grp = (unsigned)((bal >> (lane & 56)) & 0xFFull);
    const int pos = __popc(grp & ((1u << (lane & 7)) - 1u));
    if (idx >= 0) s_pair[q][pos] = make_int2(idx, __float_as_int(fw));
    if (cn == 0) s_cnt[q] = __popc(grp);
    __syncthreads();

    // ---------------- phase 2 ------------------------------------------------
    const int sg = tid >> 5;             // 0..7 subgroup
    const int c4 = (tid & 31) << 2;      // channel*4
#pragma unroll
    for (int p = 0; p < 4; ++p) {
        const int qq  = p * 8 + sg;      // 0..31
        const int gq2 = qbase + qq;
        if (gq2 >= mq) continue;
        const int cnt = s_cnt[qq];       // uniform across subgroup
        v4f acc = {0.0f, 0.0f, 0.0f, 0.0f};
        for (int j = 0; j < cnt; ++j) {
            const int2  pr = s_pair[qq][j];
            const float w  = __int_as_float(pr.y);
            const v4f   f  = *(const v4f*)&feats[(size_t)pr.x * CC + c4];
            acc += w * f;
        }
        __builtin_nontemporal_store(acc, (v4f*)&out_qf[(size_t)gq2 * CC + c4]);
    }
}

extern "C" void kernel_launch(void* const* d_in, const int* in_sizes, int n_in,
                              void* d_out, int out_size, void* d_ws, size_t ws_size,
                              hipStream_t stream) {
    const float* feats  = (const float*)d_in[0];
    const int4*  coords = (const int4*)d_in[1];
    const v4f*   qpts   = (const v4f*)d_in[2];

    const int n  = in_sizes[1] / 4;  // N points
    const int mq = in_sizes[2] / 4;  // M queries

    float* out     = (float*)d_out;
    float* out_qf  = out;
    float* out_idx = out_qf  + (size_t)mq * CC;
    float* out_w   = out_idx + (size_t)mq * 8;
    float* out_acc = out_w   + (size_t)mq * 8;

    int* shift = (int*)d_ws;
    int* occ   = (int*)((char*)d_ws + 256);

    init_kernel   <<<2048, 256, 0, stream>>>(occ, out_acc, shift, n);
    scatter_kernel<<<(n + 255) / 256, 256, 0, stream>>>(coords, shift, occ, n);
    query_kernel  <<<(mq + QPB - 1) / QPB, BLK, 0, stream>>>(
        feats, qpts, shift, occ, out_qf, out_idx, out_w, out_acc, mq);
}